// Round 20
// baseline (96.705 us; speedup 1.0000x reference)
//
#include <hip/hip_runtime.h>
#include <math.h>

#define T_LEN 6000
#define NROWS 4096          // B*C = 512*8
#define NCH 8
#define F_BINS 129
#define CF (NCH*F_BINS)     // 1032
#define NSLOT 16            // contention-splitting copies of the bary accumulator
#define REG_EPS 1e-7f

typedef _Float16 half8 __attribute__((ext_vector_type(8)));
typedef _Float16 half4_t __attribute__((ext_vector_type(4)));
typedef float f32x4 __attribute__((ext_vector_type(4)));

// ---------------- Kernel A: DFT basis, fragment-packed (round-9 code, verified) ----------------
// Bf[((nt*8+kk)*64+lane)] is a half8: element e -> B[k][n] with n=16*nt+(lane&15),
// k=32*kk+8*(lane>>4)+e. n<129: cos(2*pi*n*k/256); n>=129: sin(2*pi*(n-128)*k/256).
__global__ __launch_bounds__(256) void basis_kernel(_Float16* __restrict__ Bf) {
  int g = blockIdx.x * 256 + threadIdx.x;   // 0..8191 = (nt*8+kk)*64+lane
  int lane = g & 63;
  int ntkk = g >> 6;
  int nt = ntkk >> 3, kk = ntkk & 7;
  int n = 16 * nt + (lane & 15);
  int k0 = 32 * kk + 8 * (lane >> 4);
  half8 out;
  #pragma unroll
  for (int e = 0; e < 8; ++e) {
    int k = k0 + e;
    int m = (n < 129) ? ((n * k) & 255) : (((n - 128) * k) & 255);
    float ang = (float)m * (6.283185307179586f / 256.f);
    float v = (n < 129) ? cosf(ang) : sinf(ang);
    out[e] = (_Float16)v;
  }
  *(half8*)(Bf + (size_t)g * 8) = out;
}

// ---------------- Kernel B: Welch PSD, conv-shaped (one row per block) ----------------
// r19 insight: conv (4096 blocks, 16-deep queue/CU) does MORE work than psd in 32us vs
// 56us -- block backlog hides latency that psd's 512-block/2-resident layout exposes.
// So: grid 4096, 1 row/block, 512 threads, SINGLE-buffered LDS, cheap prologue
// (16 coalesced dwordx4 loads of fragment-packed Bf instead of 128 sincosf).
// Atomic slot = (r>>3)&15 (b-based -> 32-long chains, r16-proven).
__global__ __launch_bounds__(512) void psd_kernel(const float* __restrict__ x,
                                                  const _Float16* __restrict__ Bf,
                                                  float* __restrict__ psd,
                                                  float* __restrict__ means,
                                                  float* __restrict__ ssumN) {
  int tid = threadIdx.x;
  int lane = tid & 63;
  int w = tid >> 6;          // 0..7
  int l15 = lane & 15, l4 = lane >> 4;
  __shared__ __align__(16) _Float16 xh[6272];
  __shared__ float colsum[256];
  __shared__ float rowm[8];
  int r = blockIdx.x;

  // persistent B fragments (coalesced fragment-layout loads; L2-resident table)
  half8 bf[2][8];
  #pragma unroll
  for (int i = 0; i < 2; ++i) {
    const _Float16* bb = Bf + (size_t)(((2 * w + i) * 8) * 64 + lane) * 8;
    #pragma unroll
    for (int kk = 0; kk < 8; ++kk)
      bf[i][kk] = *(const half8*)(bb + (size_t)kk * 512);
  }

  // stage row to f16 LDS (swizzled), accumulate row sum
  const float* xr = x + (size_t)r * T_LEN;
  float rs = 0.f;
  #pragma unroll
  for (int j = 0; j < 4; ++j) {
    int c = tid + 512 * j;
    if (c < 1568) {
      float4 q = (c < 1500) ? ((const float4*)xr)[c] : make_float4(0.f, 0.f, 0.f, 0.f);
      rs += q.x + q.y + q.z + q.w;
      half4_t h = { (_Float16)q.x, (_Float16)q.y, (_Float16)q.z, (_Float16)q.w };
      int byte = 8 * c;
      byte ^= ((byte >> 8) & 7) << 4;
      *(half4_t*)((char*)xh + byte) = h;
    }
  }
  #pragma unroll
  for (int off = 32; off >= 1; off >>= 1) rs += __shfl_xor(rs, off);
  if (lane == 0) rowm[w] = rs;
  __syncthreads();                              // xh + rowm visible

  // GEMM: A[m][k]=x[128m+k] from LDS, B from regs
  f32x4 acc[2][3];
  #pragma unroll
  for (int i = 0; i < 2; ++i)
    #pragma unroll
    for (int mt = 0; mt < 3; ++mt)
      acc[i][mt] = (f32x4){0.f, 0.f, 0.f, 0.f};
  #pragma unroll
  for (int kk = 0; kk < 8; ++kk) {
    half8 a[3];
    #pragma unroll
    for (int mt = 0; mt < 3; ++mt) {
      int ab = 4096 * mt + 256 * l15 + 64 * kk + 16 * l4;
      ab ^= ((ab >> 8) & 7) << 4;
      a[mt] = *(const half8*)((const char*)xh + ab);
    }
    #pragma unroll
    for (int mt = 0; mt < 3; ++mt) {
      acc[0][mt] = __builtin_amdgcn_mfma_f32_16x16x32_f16(a[mt], bf[0][kk], acc[0][mt], 0, 0, 0);
      acc[1][mt] = __builtin_amdgcn_mfma_f32_16x16x32_f16(a[mt], bf[1][kk], acc[1][mt], 0, 0, 0);
    }
  }
  // per-lane column partials; C/D: row m = 16*mt+4*l4+j, col n = 16*nt+l15
  float s0, s1;
  #pragma unroll
  for (int i = 0; i < 2; ++i) {
    float t = 0.f;
    #pragma unroll
    for (int j = 0; j < 4; ++j) {
      t += acc[i][0][j] * acc[i][0][j];
      t += acc[i][1][j] * acc[i][1][j];
      if (4 * l4 + j < 13) t += acc[i][2][j] * acc[i][2][j];  // mask m>=45
    }
    t += __shfl_xor(t, 16);
    t += __shfl_xor(t, 32);
    if (i == 0) s0 = t; else s1 = t;
  }
  if (l4 == 0) {
    colsum[16 * (2 * w + 0) + l15] = s0;
    colsum[16 * (2 * w + 1) + l15] = s1;
  }
  __syncthreads();                              // colsum visible
  if (tid < F_BINS) {
    float vv;
    if (tid == 0) vv = 0.f;                                   // detrended DC
    else if (tid == 128) vv = colsum[128] * (1.f / 11520.f);  // Nyquist, no doubling
    else vv = (colsum[tid] + colsum[tid + 128]) * (1.f / 5760.f);
    float p = vv + REG_EPS;
    psd[(size_t)r * F_BINS + tid] = p;
    atomicAdd(&ssumN[(size_t)((r >> 3) & (NSLOT - 1)) * CF + (r & 7) * F_BINS + tid],
              sqrtf(p) * (1.f / (float)F_BINS));
  }
  if (tid == 0) {
    float ms = 0.f;
    #pragma unroll
    for (int q = 0; q < 8; ++q) ms += rowm[q];
    means[r] = ms * (1.f / (float)T_LEN);
  }
}

// ---------------- Kernel E: conv with fused filter construction (r19, unchanged) ----------------
#define BSTRIDE 296
__global__ __launch_bounds__(512) void conv_kernel(const float* __restrict__ x,
                                                   const float* __restrict__ means,
                                                   const float* __restrict__ psd,
                                                   const float* __restrict__ ssumN,
                                                   float* __restrict__ y) {
  int rc = blockIdx.x;
  int c = rc & (NCH - 1);
  int tid = threadIdx.x;
  int lane = tid & 63;
  int w = tid >> 6;          // 0..7
  __shared__ __align__(16) char smem[24576];
  _Float16* xh = (_Float16*)smem;                 // [0, 13056)
  _Float16* Bp = (_Float16*)(smem + 13056);       // [13056, 22528)
  float* part = (float*)(smem + 13056);           // overlays Bp until hv combined
  float* dv = (float*)(smem + 22528);             // [22528, 23044)
  float* hv = (float*)(smem + 23044);             // [23044, 23560)
  const float* xr = x + (size_t)rc * T_LEN;
  float mean = means[rc];
  // dv: sum the NSLOT contention-split copies (L2-resident), * rsqrt(psd)
  if (tid < F_BINS) {
    float s = 0.f;
    #pragma unroll
    for (int p = 0; p < NSLOT; ++p)
      s += ssumN[(size_t)p * CF + c * F_BINS + tid];
    dv[tid] = s * rsqrtf(psd[(size_t)rc * F_BINS + tid]);
  }
  // xh: half4 chunk q covers halves [4q,4q+4) = x float4 chunk q-32 (minus mean)
  #pragma unroll
  for (int j = 0; j < 4; ++j) {
    int q = tid + 512 * j;
    if (q < 1632) {
      int cc = q - 32;
      half4_t h;
      if (cc >= 0 && cc < 1500) {
        float4 vv = ((const float4*)xr)[cc];
        h = (half4_t){ (_Float16)(vv.x - mean), (_Float16)(vv.y - mean),
                       (_Float16)(vv.z - mean), (_Float16)(vv.w - mean) };
      } else {
        h = (half4_t){ (_Float16)0.f, (_Float16)0.f, (_Float16)0.f, (_Float16)0.f };
      }
      *(half4_t*)((char*)xh + 8 * q) = h;
    }
  }
  __syncthreads();                                // dv (and xh) visible
  // hv partials: thread 2t+p sums k in [1,63] (p=0) or [64,127] (p=1)
  if (tid < 258) {
    int t = tid >> 1, p = tid & 1;
    int k0 = p ? 64 : 1;
    int nk = p ? 64 : 63;
    float stc, sts;
    __sincosf((float)t * (6.283185307179586f / 256.f), &sts, &stc);
    float cr, ci;
    __sincosf((float)((t * k0) & 255) * (6.283185307179586f / 256.f), &ci, &cr);
    float acc = 0.f;
    for (int q = 0; q < nk; ++q) {
      acc = fmaf(dv[k0 + q], cr, acc);
      float nr = cr * stc - ci * sts;
      ci = cr * sts + ci * stc;
      cr = nr;
    }
    part[tid] = acc;
  }
  __syncthreads();                                // part visible
  if (tid < F_BINS) {
    float val = dv[0] + ((tid & 1) ? -dv[128] : dv[128]) +
                2.f * (part[2 * tid] + part[2 * tid + 1]);
    hv[tid] = val * (1.f / 256.f);
  }
  __syncthreads();                                // hv visible; part dead
  // Bp[n][4qq+e] = H[s]=hv[|s-127|], s=4qq-n-1+e (0 outside [0,256))
  #pragma unroll
  for (int j = 0; j < 3; ++j) {
    int idx = tid + 512 * j;
    if (idx < 1152) {               // 1152 = 72*16
      int n = idx & 15;
      int qq = idx >> 4;            // 0..71
      int s0 = 4 * qq - n - 1;
      half4_t h;
      #pragma unroll
      for (int e = 0; e < 4; ++e) {
        int s = s0 + e;
        float hvv = 0.f;
        if (s >= 0 && s < 256) {
          int ii = s - 127; if (ii < 0) ii = -ii;
          hvv = hv[ii];
        }
        h[e] = (_Float16)hvv;
      }
      *(half4_t*)((char*)Bp + (size_t)n * (2 * BSTRIDE) + 8 * qq) = h;
    }
  }
  __syncthreads();

  int l15 = lane & 15, l4 = lane >> 4;
  f32x4 acc0 = {0.f,0.f,0.f,0.f}, acc1 = {0.f,0.f,0.f,0.f}, acc2 = {0.f,0.f,0.f,0.f};
  const _Float16* bbase = &Bp[BSTRIDE * l15 + 8 * l4];
  const _Float16* abase = &xh[16 * l15 + 8 * l4 + 768 * w];   // tile mt = 3w+i
  #pragma unroll
  for (int kk = 0; kk < 9; ++kk) {
    half8 b = *(const half8*)(bbase + 32 * kk);
    half8 a0 = *(const half8*)(abase + 32 * kk);
    half8 a1 = *(const half8*)(abase + 256 + 32 * kk);
    half8 a2 = *(const half8*)(abase + 512 + 32 * kk);
    acc0 = __builtin_amdgcn_mfma_f32_16x16x32_f16(a0, b, acc0, 0, 0, 0);
    acc1 = __builtin_amdgcn_mfma_f32_16x16x32_f16(a1, b, acc1, 0, 0, 0);
    acc2 = __builtin_amdgcn_mfma_f32_16x16x32_f16(a2, b, acc2, 0, 0, 0);
  }
  __syncthreads();                 // all GEMM LDS reads done; smem reusable
  // bounce: wave w's region = floats [768w, 768w+768)
  float* bw = (float*)smem + 768 * w;
  #pragma unroll
  for (int i = 0; i < 3; ++i) {
    f32x4 a = (i == 0) ? acc0 : (i == 1) ? acc1 : acc2;
    #pragma unroll
    for (int j = 0; j < 4; ++j)
      bw[256 * i + 64 * l4 + 16 * j + l15] = a[j];
  }
  // coalesced store: lane reads its own wave's region (within-wave dep, no barrier)
  float* yr = y + (size_t)rc * T_LEN + 768 * w;
  const float4* b4 = (const float4*)bw;
  #pragma unroll
  for (int cc = 0; cc < 3; ++cc) {
    int fi = 768 * w + 256 * cc + 4 * lane;
    if (fi < T_LEN)
      *(float4*)&yr[256 * cc + 4 * lane] = b4[64 * cc + lane];
  }
}

extern "C" void kernel_launch(void* const* d_in, const int* in_sizes, int n_in,
                              void* d_out, int out_size, void* d_ws, size_t ws_size,
                              hipStream_t stream) {
  const float* x = (const float*)d_in[0];
  float* out = (float*)d_out;
  float* psd   = (float*)d_ws;                         //   528,384 f
  float* ssumN = psd + (size_t)NROWS * F_BINS;         // 16*1,032 f
  float* means = ssumN + (size_t)NSLOT * CF;           //     4,096 f
  _Float16* Bf = (_Float16*)(means + NROWS);           //    65,536 f16
  hipMemsetAsync(ssumN, 0, (size_t)NSLOT * CF * sizeof(float), stream);
  basis_kernel<<<32, 256, 0, stream>>>(Bf);
  psd_kernel<<<NROWS, 512, 0, stream>>>(x, Bf, psd, means, ssumN);
  conv_kernel<<<NROWS, 512, 0, stream>>>(x, means, psd, ssumN, out);
}